// Round 1
// baseline (1501.969 us; speedup 1.0000x reference)
//
#include <hip/hip_runtime.h>

#define B_ 512
#define T_ 1024
#define F_ 32
#define H0_ 64
#define H1_ 32
#define CHUNK 64
#define NCHUNK (T_ / CHUNK)
#define NT 128

// fast sigmoid / tanh via v_exp_f32 + v_rcp_f32
__device__ __forceinline__ float sigmoid_f(float x) {
    return __builtin_amdgcn_rcpf(1.0f + __expf(-x));
}
__device__ __forceinline__ float tanh_f(float x) {
    // 2*sigmoid(2x) - 1
    return fmaf(2.0f, __builtin_amdgcn_rcpf(1.0f + __expf(-2.0f * x)), -1.0f);
}
// branchless: A * sigmoid(S*x) + C   (sigmoid: S=1,A=1,C=0; tanh: S=2,A=2,C=-1)
__device__ __forceinline__ float act_f(float x, float S, float A, float C) {
    float e = __expf(-S * x);
    return fmaf(A, __builtin_amdgcn_rcpf(1.0f + e), C);
}

__global__ void __launch_bounds__(NT, 1) lstm2_kernel(
    const float* __restrict__ x,
    const float* __restrict__ Wih0, const float* __restrict__ Whh0,
    const float* __restrict__ bih0, const float* __restrict__ bhh0,
    const float* __restrict__ Wih1, const float* __restrict__ Whh1,
    const float* __restrict__ bih1, const float* __restrict__ bhh1,
    const float* __restrict__ fcw, const float* __restrict__ fcb,
    float* __restrict__ out)
{
    __shared__ __align__(16) float xbuf[2][CHUNK][F_];
    __shared__ __align__(16) float h0buf[2][H0_];
    __shared__ __align__(16) float h1buf[2][H1_];

    const int tid = threadIdx.x;
    const int b = blockIdx.x;

    // Layer0: lane pair (2u, 2u+1) owns unit u. sub=0 lane: gates i_u (row u), f_u (row u+64).
    //         sub=1 lane: gates g_u (row u+128), o_u (row u+192).
    const int u0 = tid >> 1, sub = tid & 1;
    // Layer1: lane quad (4v..4v+3) owns unit v; q = gate type (i,f,g,o).
    const int v1 = tid >> 2, q = tid & 3;
    const int r0a = u0 + sub * 128;        // i or g row
    const int r0b = u0 + 64 + sub * 128;   // f or o row
    const int r1  = v1 + q * 32;

    // ---- weights in registers (288 floats/thread) ----
    float wih0a[F_], wih0b[F_], whh0a[H0_], whh0b[H0_], wih1[H0_], whh1[H1_];
#pragma unroll
    for (int k = 0; k < F_; ++k) { wih0a[k] = Wih0[r0a * F_ + k]; wih0b[k] = Wih0[r0b * F_ + k]; }
#pragma unroll
    for (int k = 0; k < H0_; ++k) { whh0a[k] = Whh0[r0a * H0_ + k]; whh0b[k] = Whh0[r0b * H0_ + k]; }
#pragma unroll
    for (int k = 0; k < H0_; ++k) wih1[k] = Wih1[r1 * H0_ + k];
#pragma unroll
    for (int k = 0; k < H1_; ++k) whh1[k] = Whh1[r1 * H1_ + k];

    const float bias0a = bih0[r0a] + bhh0[r0a];
    const float bias0b = bih0[r0b] + bhh0[r0b];
    const float bias1  = bih1[r1] + bhh1[r1];

    // activation constants (branchless, per-thread uniform constants)
    const float Sa = sub ? 2.0f : 1.0f;   // acc_a: sub=1 is g-gate -> tanh
    const float Aa = sub ? 2.0f : 1.0f;
    const float Ca = sub ? -1.0f : 0.0f;
    const float S1 = (q == 2) ? 2.0f : 1.0f;  // layer1: q==2 is g-gate -> tanh
    const float A1 = (q == 2) ? 2.0f : 1.0f;
    const float C1 = (q == 2) ? -1.0f : 0.0f;

    const float* xb = x + (size_t)b * T_ * F_;

    // stage chunk 0 (8 KB contiguous) + init state
    {
        const float4* src = (const float4*)xb;
        float4* dst = (float4*)&xbuf[0][0][0];
#pragma unroll
        for (int i = 0; i < 4; ++i) dst[tid + i * NT] = src[tid + i * NT];
    }
    if (tid < H0_) h0buf[0][tid] = 0.0f;
    if (tid < H1_) h1buf[0][tid] = 0.0f;
    float c0 = 0.0f, c1 = 0.0f;
    __syncthreads();

    int p = 0, cb = 0;
    for (int chunk = 0; chunk < NCHUNK; ++chunk) {
        float4 pre[4];
        const bool more = (chunk + 1 < NCHUNK);
        if (more) {
            const float4* src = (const float4*)(xb + (size_t)(chunk + 1) * CHUNK * F_);
#pragma unroll
            for (int i = 0; i < 4; ++i) pre[i] = src[tid + i * NT];  // prefetch: latency hidden under 64 steps
        }
#pragma unroll 1
        for (int s = 0; s < CHUNK; ++s) {
            const int pn = p ^ 1;
            // ---------- phase A: layer0 gates (2 per thread) ----------
            float a0 = 0.f, a1p = 0.f, b0 = 0.f, b1p = 0.f;  // 4 independent FMA chains
            const float4* xr = (const float4*)&xbuf[cb][s][0];
#pragma unroll
            for (int j = 0; j < F_ / 4; ++j) {
                float4 v = xr[j];
                a0  = fmaf(wih0a[4 * j + 0], v.x, a0);
                b0  = fmaf(wih0b[4 * j + 0], v.x, b0);
                a1p = fmaf(wih0a[4 * j + 1], v.y, a1p);
                b1p = fmaf(wih0b[4 * j + 1], v.y, b1p);
                a0  = fmaf(wih0a[4 * j + 2], v.z, a0);
                b0  = fmaf(wih0b[4 * j + 2], v.z, b0);
                a1p = fmaf(wih0a[4 * j + 3], v.w, a1p);
                b1p = fmaf(wih0b[4 * j + 3], v.w, b1p);
            }
            const float4* hr = (const float4*)&h0buf[p][0];
#pragma unroll
            for (int j = 0; j < H0_ / 4; ++j) {
                float4 v = hr[j];
                a0  = fmaf(whh0a[4 * j + 0], v.x, a0);
                b0  = fmaf(whh0b[4 * j + 0], v.x, b0);
                a1p = fmaf(whh0a[4 * j + 1], v.y, a1p);
                b1p = fmaf(whh0b[4 * j + 1], v.y, b1p);
                a0  = fmaf(whh0a[4 * j + 2], v.z, a0);
                b0  = fmaf(whh0b[4 * j + 2], v.z, b0);
                a1p = fmaf(whh0a[4 * j + 3], v.w, a1p);
                b1p = fmaf(whh0b[4 * j + 3], v.w, b1p);
            }
            float ga = act_f(bias0a + (a0 + a1p), Sa, Aa, Ca);   // i (sub0) or g (sub1)
            float gb = sigmoid_f(bias0b + (b0 + b1p));           // f (sub0) or o (sub1)
            // ---------- phase B: cell update via lane-pair shuffle ----------
            float xg = __shfl_xor(ga, 1, 64);  // sub0 lane receives g
            float xo = __shfl_xor(gb, 1, 64);  // sub0 lane receives o
            if (sub == 0) {
                c0 = fmaf(gb, c0, ga * xg);            // c = f*c + i*g
                h0buf[pn][u0] = xo * tanh_f(c0);       // h = o*tanh(c)
            }
            __syncthreads();  // the ONE barrier/step: h0 new -> layer1 input
            // ---------- phase C: layer1 gate (1 per thread) ----------
            float p0 = 0.f, p1 = 0.f, p2 = 0.f, p3 = 0.f;
            const float4* h0r = (const float4*)&h0buf[pn][0];
#pragma unroll
            for (int j = 0; j < H0_ / 4; ++j) {
                float4 v = h0r[j];
                p0 = fmaf(wih1[4 * j + 0], v.x, p0);
                p1 = fmaf(wih1[4 * j + 1], v.y, p1);
                p2 = fmaf(wih1[4 * j + 2], v.z, p2);
                p3 = fmaf(wih1[4 * j + 3], v.w, p3);
            }
            const float4* h1r = (const float4*)&h1buf[p][0];
#pragma unroll
            for (int j = 0; j < H1_ / 4; ++j) {
                float4 v = h1r[j];
                p0 = fmaf(whh1[4 * j + 0], v.x, p0);
                p1 = fmaf(whh1[4 * j + 1], v.y, p1);
                p2 = fmaf(whh1[4 * j + 2], v.z, p2);
                p3 = fmaf(whh1[4 * j + 3], v.w, p3);
            }
            float g1 = act_f(bias1 + ((p0 + p1) + (p2 + p3)), S1, A1, C1);
            // ---------- phase D: layer1 cell update via quad shuffles ----------
            float e1 = __shfl_xor(g1, 1, 64);  // q0 lane: f
            float e2 = __shfl_xor(g1, 2, 64);  // q0 lane: g
            float e3 = __shfl_xor(e1, 2, 64);  // q0 lane: o
            if (q == 0) {
                c1 = fmaf(e1, c1, g1 * e2);
                h1buf[pn][v1] = e3 * tanh_f(c1);
            }
            p = pn;
        }
        if (more) {
            float4* dst = (float4*)&xbuf[cb ^ 1][0][0];
#pragma unroll
            for (int i = 0; i < 4; ++i) dst[tid + i * NT] = pre[i];
        }
        __syncthreads();
        cb ^= 1;
    }

    // ---------- epilogue: out[B], hT0[B,64], cT0[B,64], hT1[B,32], cT1[B,32] ----------
    float* hT0 = out + B_;
    float* cT0 = hT0 + B_ * H0_;
    float* hT1 = cT0 + B_ * H0_;
    float* cT1 = hT1 + B_ * H1_;
    if (tid < H0_) hT0[b * H0_ + tid] = h0buf[p][tid];
    if (sub == 0) cT0[b * H0_ + u0] = c0;          // even lanes hold c0 for unit u0 (0..63)
    if (tid < H1_) hT1[b * H1_ + tid] = h1buf[p][tid];
    if (q == 0) cT1[b * H1_ + v1] = c1;            // quad-leader lanes hold c1 (0..31)
    if (tid < H1_) {
        float partial = h1buf[p][tid] * fcw[tid];
#pragma unroll
        for (int m = 16; m >= 1; m >>= 1) partial += __shfl_xor(partial, m, 64);
        if (tid == 0) out[b] = partial + fcb[0];
    }
}

extern "C" void kernel_launch(void* const* d_in, const int* in_sizes, int n_in,
                              void* d_out, int out_size, void* d_ws, size_t ws_size,
                              hipStream_t stream) {
    const float* x    = (const float*)d_in[0];
    const float* Wih0 = (const float*)d_in[1];
    const float* Whh0 = (const float*)d_in[2];
    const float* bih0 = (const float*)d_in[3];
    const float* bhh0 = (const float*)d_in[4];
    const float* Wih1 = (const float*)d_in[5];
    const float* Whh1 = (const float*)d_in[6];
    const float* bih1 = (const float*)d_in[7];
    const float* bhh1 = (const float*)d_in[8];
    const float* fcw  = (const float*)d_in[9];
    const float* fcb  = (const float*)d_in[10];

    hipLaunchKernelGGL(lstm2_kernel, dim3(B_), dim3(NT), 0, stream,
                       x, Wih0, Whh0, bih0, bhh0, Wih1, Whh1, bih1, bhh1,
                       fcw, fcb, (float*)d_out);
}

// Round 2
// 1109.013 us; speedup vs baseline: 1.3543x; 1.3543x over previous
//
#include <hip/hip_runtime.h>

#define B_ 512
#define T_ 1024
#define F_ 32
#define H0_ 64
#define H1_ 32
#define CHUNK 64
#define NCHUNK (T_ / CHUNK)
#define NT 256

// fast sigmoid / tanh via v_exp_f32 + v_rcp_f32
__device__ __forceinline__ float sigmoid_f(float x) {
    return __builtin_amdgcn_rcpf(1.0f + __expf(-x));
}
__device__ __forceinline__ float tanh_f(float x) {
    return fmaf(2.0f, __builtin_amdgcn_rcpf(1.0f + __expf(-2.0f * x)), -1.0f);
}
// branchless: A * sigmoid(S*x) + C   (sigmoid: S=1,A=1,C=0; tanh: S=2,A=2,C=-1)
__device__ __forceinline__ float act_f(float x, float S, float A, float C) {
    float e = __expf(-S * x);
    return fmaf(A, __builtin_amdgcn_rcpf(1.0f + e), C);
}

__global__ void __launch_bounds__(NT, 2) lstm2_kernel(
    const float* __restrict__ x,
    const float* __restrict__ Wih0, const float* __restrict__ Whh0,
    const float* __restrict__ bih0, const float* __restrict__ bhh0,
    const float* __restrict__ Wih1, const float* __restrict__ Whh1,
    const float* __restrict__ bih1, const float* __restrict__ bhh1,
    const float* __restrict__ fcw, const float* __restrict__ fcb,
    float* __restrict__ out)
{
    __shared__ __align__(16) float xbuf[2][CHUNK][F_];
    __shared__ __align__(16) float h0buf[2][H0_];
    __shared__ __align__(16) float h1buf[2][H1_];

    const int tid = threadIdx.x;
    const int b = blockIdx.x;

    // Layer0: thread owns one gate row. u = unit, q = gate (0:i 1:f 2:g 3:o).
    const int u0 = tid >> 2, q0 = tid & 3;
    const int r0 = q0 * H0_ + u0;
    // Layer1: 8 lanes per unit. v = unit, q1 = gate, half = which half of the dot.
    const int v1 = tid >> 3, q1 = (tid >> 1) & 3, half = tid & 1;
    const int r1 = q1 * H1_ + v1;

    // ---- weights in registers (96 + 48 = 144 floats/thread) ----
    float wih0[F_], whh0[H0_], wih1[F_], whh1[H1_ / 2];
#pragma unroll
    for (int k = 0; k < F_; ++k) wih0[k] = Wih0[r0 * F_ + k];
#pragma unroll
    for (int k = 0; k < H0_; ++k) whh0[k] = Whh0[r0 * H0_ + k];
#pragma unroll
    for (int k = 0; k < F_; ++k) wih1[k] = Wih1[r1 * H0_ + half * 32 + k];
#pragma unroll
    for (int k = 0; k < H1_ / 2; ++k) whh1[k] = Whh1[r1 * H1_ + half * 16 + k];

    const float bias0 = bih0[r0] + bhh0[r0];
    const float bias1 = bih1[r1] + bhh1[r1];

    // activation constants (per-thread uniform, branchless)
    const float S0 = (q0 == 2) ? 2.0f : 1.0f;
    const float A0 = (q0 == 2) ? 2.0f : 1.0f;
    const float C0 = (q0 == 2) ? -1.0f : 0.0f;
    const float S1 = (q1 == 2) ? 2.0f : 1.0f;
    const float A1 = (q1 == 2) ? 2.0f : 1.0f;
    const float C1 = (q1 == 2) ? -1.0f : 0.0f;

    const float* xb = x + (size_t)b * T_ * F_;

    // stage chunk 0 (8 KB contiguous: 512 float4, 2 per thread) + init state
    {
        const float4* src = (const float4*)xb;
        float4* dst = (float4*)&xbuf[0][0][0];
#pragma unroll
        for (int i = 0; i < 2; ++i) dst[tid + i * NT] = src[tid + i * NT];
    }
    if (tid < H0_) h0buf[0][tid] = 0.0f;
    if (tid < H1_) h1buf[0][tid] = 0.0f;
    float c0 = 0.0f, c1 = 0.0f;
    __syncthreads();

    int p = 0, cb = 0;
    for (int chunk = 0; chunk < NCHUNK; ++chunk) {
        float4 pre[2];
        const bool more = (chunk + 1 < NCHUNK);
        if (more) {
            const float4* src = (const float4*)(xb + (size_t)(chunk + 1) * CHUNK * F_);
#pragma unroll
            for (int i = 0; i < 2; ++i) pre[i] = src[tid + i * NT];  // latency hidden under 64 steps
        }
#pragma unroll 1
        for (int s = 0; s < CHUNK; ++s) {
            const int pn = p ^ 1;
            // ---------- phase A: layer0, one gate row per thread (96 FMA) ----------
            float a0 = 0.f, a1 = 0.f, a2 = 0.f, a3 = 0.f;  // 4 independent chains
            const float4* xr = (const float4*)&xbuf[cb][s][0];
#pragma unroll
            for (int j = 0; j < F_ / 4; ++j) {
                float4 v = xr[j];
                a0 = fmaf(wih0[4 * j + 0], v.x, a0);
                a1 = fmaf(wih0[4 * j + 1], v.y, a1);
                a2 = fmaf(wih0[4 * j + 2], v.z, a2);
                a3 = fmaf(wih0[4 * j + 3], v.w, a3);
            }
            const float4* hr = (const float4*)&h0buf[p][0];
#pragma unroll
            for (int j = 0; j < H0_ / 4; ++j) {
                float4 v = hr[j];
                a0 = fmaf(whh0[4 * j + 0], v.x, a0);
                a1 = fmaf(whh0[4 * j + 1], v.y, a1);
                a2 = fmaf(whh0[4 * j + 2], v.z, a2);
                a3 = fmaf(whh0[4 * j + 3], v.w, a3);
            }
            float g0 = act_f(bias0 + ((a0 + a1) + (a2 + a3)), S0, A0, C0);
            // quad combine: lane q0==0 gathers f,g,o
            float xf = __shfl_xor(g0, 1, 64);
            float xg = __shfl_xor(g0, 2, 64);
            float xo = __shfl_xor(xf, 2, 64);
            if (q0 == 0) {
                c0 = fmaf(xf, c0, g0 * xg);          // c = f*c + i*g
                h0buf[pn][u0] = xo * tanh_f(c0);     // h = o*tanh(c)
            }
            __syncthreads();  // the ONE barrier/step: new h0 -> layer1
            // ---------- phase C: layer1, half gate row per thread (48 FMA) ----------
            float p0 = 0.f, p1 = 0.f, p2 = 0.f, p3 = 0.f;
            const float4* h0r = (const float4*)&h0buf[pn][half * 32];
#pragma unroll
            for (int j = 0; j < 8; ++j) {
                float4 v = h0r[j];
                p0 = fmaf(wih1[4 * j + 0], v.x, p0);
                p1 = fmaf(wih1[4 * j + 1], v.y, p1);
                p2 = fmaf(wih1[4 * j + 2], v.z, p2);
                p3 = fmaf(wih1[4 * j + 3], v.w, p3);
            }
            const float4* h1r = (const float4*)&h1buf[p][half * 16];
#pragma unroll
            for (int j = 0; j < 4; ++j) {
                float4 v = h1r[j];
                p0 = fmaf(whh1[4 * j + 0], v.x, p0);
                p1 = fmaf(whh1[4 * j + 1], v.y, p1);
                p2 = fmaf(whh1[4 * j + 2], v.z, p2);
                p3 = fmaf(whh1[4 * j + 3], v.w, p3);
            }
            float acc1 = (p0 + p1) + (p2 + p3);
            float s1 = acc1 + __shfl_xor(acc1, 1, 64);          // join halves
            float g1 = act_f(bias1 + s1, S1, A1, C1);
            float yf = __shfl_xor(g1, 2, 64);
            float yg = __shfl_xor(g1, 4, 64);
            float yo = __shfl_xor(yf, 4, 64);
            if ((tid & 7) == 0) {
                c1 = fmaf(yf, c1, g1 * yg);
                h1buf[pn][v1] = yo * tanh_f(c1);
            }
            p = pn;
        }
        if (more) {
            float4* dst = (float4*)&xbuf[cb ^ 1][0][0];
#pragma unroll
            for (int i = 0; i < 2; ++i) dst[tid + i * NT] = pre[i];
        }
        __syncthreads();
        cb ^= 1;
    }

    // ---------- epilogue: out[B], hT0[B,64], cT0[B,64], hT1[B,32], cT1[B,32] ----------
    float* hT0 = out + B_;
    float* cT0 = hT0 + B_ * H0_;
    float* hT1 = cT0 + B_ * H0_;
    float* cT1 = hT1 + B_ * H1_;
    if (tid < H0_) hT0[b * H0_ + tid] = h0buf[p][tid];
    if (q0 == 0) cT0[b * H0_ + u0] = c0;            // lanes 4u hold c0 of unit u
    if (tid < H1_) hT1[b * H1_ + tid] = h1buf[p][tid];
    if ((tid & 7) == 0) cT1[b * H1_ + v1] = c1;     // lanes 8v hold c1 of unit v
    if (tid < H1_) {
        float partial = h1buf[p][tid] * fcw[tid];
#pragma unroll
        for (int m = 16; m >= 1; m >>= 1) partial += __shfl_xor(partial, m, 64);
        if (tid == 0) out[b] = partial + fcb[0];
    }
}

extern "C" void kernel_launch(void* const* d_in, const int* in_sizes, int n_in,
                              void* d_out, int out_size, void* d_ws, size_t ws_size,
                              hipStream_t stream) {
    const float* x    = (const float*)d_in[0];
    const float* Wih0 = (const float*)d_in[1];
    const float* Whh0 = (const float*)d_in[2];
    const float* bih0 = (const float*)d_in[3];
    const float* bhh0 = (const float*)d_in[4];
    const float* Wih1 = (const float*)d_in[5];
    const float* Whh1 = (const float*)d_in[6];
    const float* bih1 = (const float*)d_in[7];
    const float* bhh1 = (const float*)d_in[8];
    const float* fcw  = (const float*)d_in[9];
    const float* fcb  = (const float*)d_in[10];

    hipLaunchKernelGGL(lstm2_kernel, dim3(B_), dim3(NT), 0, stream,
                       x, Wih0, Whh0, bih0, bhh0, Wih1, Whh1, bih1, bhh1,
                       fcw, fcb, (float*)d_out);
}

// Round 4
// 943.195 us; speedup vs baseline: 1.5924x; 1.1758x over previous
//
#include <hip/hip_runtime.h>

#define B_ 512
#define T_ 1024
#define F_ 32
#define H0_ 64
#define H1_ 32
#define CHUNK 64
#define NCHUNK (T_ / CHUNK)
#define NT 256

typedef _Float16 h2 __attribute__((ext_vector_type(2)));
typedef _Float16 h4 __attribute__((ext_vector_type(4)));
typedef _Float16 h8 __attribute__((ext_vector_type(8)));

__device__ __forceinline__ float fdot2(h2 a, h2 b, float c) {
#if defined(__has_builtin)
#if __has_builtin(__builtin_amdgcn_fdot2)
    return __builtin_amdgcn_fdot2(a, b, c, false);
#else
    return c + (float)a[0] * (float)b[0] + (float)a[1] * (float)b[1];
#endif
#else
    return c + (float)a[0] * (float)b[0] + (float)a[1] * (float)b[1];
#endif
}

// quad-local butterfly add via DPP quad_perm (VALU, no LDS pipe)
// xor1: perm [1,0,3,2] = 0xB1 ; xor2: perm [2,3,0,1] = 0x4E
template <int CTRL>
__device__ __forceinline__ float dpp_add(float v) {
    int t = __builtin_amdgcn_update_dpp(0, __float_as_int(v), CTRL, 0xF, 0xF, true);
    return v + __int_as_float(t);
}

__device__ __forceinline__ float sigmoid_f(float x) {
    return __builtin_amdgcn_rcpf(1.0f + __expf(-x));
}
__device__ __forceinline__ float tanh_f(float x) {
    return fmaf(2.0f, __builtin_amdgcn_rcpf(1.0f + __expf(-2.0f * x)), -1.0f);
}

__device__ __forceinline__ h4 cvt_h4(float4 v) {
    h4 o;
    o[0] = (_Float16)v.x; o[1] = (_Float16)v.y;
    o[2] = (_Float16)v.z; o[3] = (_Float16)v.w;
    return o;
}

// extract h2 pair j from an h8 (bit-reinterpret, no element moves)
__device__ __forceinline__ h2 pair8(h8 v, int j) {
    union { h8 v8; h2 v2[4]; } u; u.v8 = v; return u.v2[j];
}
__device__ __forceinline__ h2 pair4(h4 v, int j) {
    union { h4 v4; h2 v2[2]; } u; u.v4 = v; return u.v2[j];
}

__global__ void __launch_bounds__(NT, 2) lstm2_kernel(
    const float* __restrict__ x,
    const float* __restrict__ Wih0, const float* __restrict__ Whh0,
    const float* __restrict__ bih0, const float* __restrict__ bhh0,
    const float* __restrict__ Wih1, const float* __restrict__ Whh1,
    const float* __restrict__ bih1, const float* __restrict__ bhh1,
    const float* __restrict__ fcw, const float* __restrict__ fcb,
    float* __restrict__ out)
{
    __shared__ __align__(16) _Float16 xbuf[2][CHUNK][F_];   // 8 KB
    __shared__ __align__(16) _Float16 h0buf[2][H0_];
    __shared__ __align__(16) _Float16 h1buf[2][H1_];
    __shared__ float h1fin[H1_];

    const int tid = threadIdx.x;
    const int b = blockIdx.x;
    const int l = tid & 63, w = tid >> 6;

    // Layer0: one quad per unit; lane qt owns quarter-dots of ALL 4 gates of unit u.
    const int u = w * 16 + (l >> 2), qt = l & 3;
    // Layer1: one oct per unit; lane e owns eighth-dots of all 4 gates of unit v.
    const int v1 = w * 8 + (l >> 3), e = l & 7;

    // ---- weights in arch VGPRs as f16 pairs (72 VGPRs total) ----
    h2 w0x[4][4], w0h[4][8];   // L0: per gate: x cols [8qt..+8), h cols [16qt..+16)
    h2 w1a[4][4], w1b[4][2];   // L1: per gate: h0 cols [8e..+8), h1 cols [4e..+4)
    float bias0[4], bias1[4];
#pragma unroll
    for (int g = 0; g < 4; ++g) {
        const int r = g * H0_ + u;
#pragma unroll
        for (int j = 0; j < 4; ++j) {
            float2 f = *(const float2*)&Wih0[r * F_ + 8 * qt + 2 * j];
            w0x[g][j][0] = (_Float16)f.x; w0x[g][j][1] = (_Float16)f.y;
        }
#pragma unroll
        for (int j = 0; j < 8; ++j) {
            float2 f = *(const float2*)&Whh0[r * H0_ + 16 * qt + 2 * j];
            w0h[g][j][0] = (_Float16)f.x; w0h[g][j][1] = (_Float16)f.y;
        }
        bias0[g] = bih0[r] + bhh0[r];
    }
#pragma unroll
    for (int g = 0; g < 4; ++g) {
        const int r = g * H1_ + v1;
#pragma unroll
        for (int j = 0; j < 4; ++j) {
            float2 f = *(const float2*)&Wih1[r * H0_ + 8 * e + 2 * j];
            w1a[g][j][0] = (_Float16)f.x; w1a[g][j][1] = (_Float16)f.y;
        }
#pragma unroll
        for (int j = 0; j < 2; ++j) {
            float2 f = *(const float2*)&Whh1[r * H1_ + 4 * e + 2 * j];
            w1b[g][j][0] = (_Float16)f.x; w1b[g][j][1] = (_Float16)f.y;
        }
        bias1[g] = bih1[r] + bhh1[r];
    }

    const float* xb = x + (size_t)b * T_ * F_;

    // stage chunk 0 (fp32 -> f16), init state
    {
        float4 v0 = ((const float4*)xb)[tid];
        float4 v1 = ((const float4*)xb)[tid + NT];
        *(h4*)&(&xbuf[0][0][0])[tid * 4] = cvt_h4(v0);
        *(h4*)&(&xbuf[0][0][0])[(tid + NT) * 4] = cvt_h4(v1);
    }
    if (tid < H0_) h0buf[0][tid] = (_Float16)0.0f;
    if (tid < H1_) h1buf[0][tid] = (_Float16)0.0f;
    float c0 = 0.0f, c1 = 0.0f, h0f = 0.0f, h1f = 0.0f;
    __syncthreads();

    int p = 0, cb = 0;
    for (int chunk = 0; chunk < NCHUNK; ++chunk) {
        float4 pre0, pre1;
        const bool more = (chunk + 1 < NCHUNK);
        if (more) {
            const float4* src = (const float4*)(xb + (size_t)(chunk + 1) * CHUNK * F_);
            pre0 = src[tid];
            pre1 = src[tid + NT];
        }
#pragma unroll 1
        for (int s = 0; s < CHUNK; ++s) {
            const int pn = p ^ 1;
            // ---------- layer 0: quarter-dots of 4 gates ----------
            h8 xv = *(const h8*)&xbuf[cb][s][8 * qt];
            h8 ha = *(const h8*)&h0buf[p][16 * qt];
            h8 hb = *(const h8*)&h0buf[p][16 * qt + 8];
            float a0 = 0.f, a1 = 0.f, a2 = 0.f, a3 = 0.f;
#pragma unroll
            for (int j = 0; j < 4; ++j) {
                h2 xx = pair8(xv, j);
                a0 = fdot2(w0x[0][j], xx, a0);
                a1 = fdot2(w0x[1][j], xx, a1);
                a2 = fdot2(w0x[2][j], xx, a2);
                a3 = fdot2(w0x[3][j], xx, a3);
            }
#pragma unroll
            for (int j = 0; j < 4; ++j) {
                h2 hh = pair8(ha, j);
                a0 = fdot2(w0h[0][j], hh, a0);
                a1 = fdot2(w0h[1][j], hh, a1);
                a2 = fdot2(w0h[2][j], hh, a2);
                a3 = fdot2(w0h[3][j], hh, a3);
            }
#pragma unroll
            for (int j = 0; j < 4; ++j) {
                h2 hh = pair8(hb, j);
                a0 = fdot2(w0h[0][4 + j], hh, a0);
                a1 = fdot2(w0h[1][4 + j], hh, a1);
                a2 = fdot2(w0h[2][4 + j], hh, a2);
                a3 = fdot2(w0h[3][4 + j], hh, a3);
            }
            // quad all-reduce via DPP (every lane gets all 4 gate sums)
            a0 = dpp_add<0xB1>(a0); a0 = dpp_add<0x4E>(a0);
            a1 = dpp_add<0xB1>(a1); a1 = dpp_add<0x4E>(a1);
            a2 = dpp_add<0xB1>(a2); a2 = dpp_add<0x4E>(a2);
            a3 = dpp_add<0xB1>(a3); a3 = dpp_add<0x4E>(a3);
            float gi = sigmoid_f(bias0[0] + a0);
            float gf = sigmoid_f(bias0[1] + a1);
            float gg = tanh_f(bias0[2] + a2);
            float go = sigmoid_f(bias0[3] + a3);
            c0 = fmaf(gf, c0, gi * gg);
            h0f = go * tanh_f(c0);
            if (qt == 0) h0buf[pn][u] = (_Float16)h0f;
            __syncthreads();  // the ONE barrier/step: new h0 -> layer1
            // ---------- layer 1: eighth-dots of 4 gates ----------
            h8 pa = *(const h8*)&h0buf[pn][8 * e];
            h4 pb = *(const h4*)&h1buf[p][4 * e];
            float q0 = 0.f, q1 = 0.f, q2 = 0.f, q3 = 0.f;
#pragma unroll
            for (int j = 0; j < 4; ++j) {
                h2 hh = pair8(pa, j);
                q0 = fdot2(w1a[0][j], hh, q0);
                q1 = fdot2(w1a[1][j], hh, q1);
                q2 = fdot2(w1a[2][j], hh, q2);
                q3 = fdot2(w1a[3][j], hh, q3);
            }
#pragma unroll
            for (int j = 0; j < 2; ++j) {
                h2 hh = pair4(pb, j);
                q0 = fdot2(w1b[0][j], hh, q0);
                q1 = fdot2(w1b[1][j], hh, q1);
                q2 = fdot2(w1b[2][j], hh, q2);
                q3 = fdot2(w1b[3][j], hh, q3);
            }
            // oct join: xor4 via shuffle, then quad DPP all-reduce
            q0 += __shfl_xor(q0, 4, 64);
            q1 += __shfl_xor(q1, 4, 64);
            q2 += __shfl_xor(q2, 4, 64);
            q3 += __shfl_xor(q3, 4, 64);
            q0 = dpp_add<0xB1>(q0); q0 = dpp_add<0x4E>(q0);
            q1 = dpp_add<0xB1>(q1); q1 = dpp_add<0x4E>(q1);
            q2 = dpp_add<0xB1>(q2); q2 = dpp_add<0x4E>(q2);
            q3 = dpp_add<0xB1>(q3); q3 = dpp_add<0x4E>(q3);
            float ji = sigmoid_f(bias1[0] + q0);
            float jf = sigmoid_f(bias1[1] + q1);
            float jg = tanh_f(bias1[2] + q2);
            float jo = sigmoid_f(bias1[3] + q3);
            c1 = fmaf(jf, c1, ji * jg);
            h1f = jo * tanh_f(c1);
            if (e == 0) h1buf[pn][v1] = (_Float16)h1f;
            p = pn;
        }
        if (more) {
            _Float16* dst = &xbuf[cb ^ 1][0][0];
            *(h4*)&dst[tid * 4] = cvt_h4(pre0);
            *(h4*)&dst[(tid + NT) * 4] = cvt_h4(pre1);
        }
        __syncthreads();
        cb ^= 1;
    }

    // ---------- epilogue: out[B], hT0[B,64], cT0[B,64], hT1[B,32], cT1[B,32] ----------
    float* hT0 = out + B_;
    float* cT0 = hT0 + B_ * H0_;
    float* hT1 = cT0 + B_ * H0_;
    float* cT1 = hT1 + B_ * H1_;
    if (qt == 0) { hT0[b * H0_ + u] = h0f; cT0[b * H0_ + u] = c0; }
    if (e == 0)  { hT1[b * H1_ + v1] = h1f; cT1[b * H1_ + v1] = c1; h1fin[v1] = h1f; }
    __syncthreads();
    if (tid < H1_) {
        float pr = h1fin[tid] * fcw[tid];
        pr += __shfl_xor(pr, 16, 64);
        pr += __shfl_xor(pr, 8, 64);
        pr += __shfl_xor(pr, 4, 64);
        pr += __shfl_xor(pr, 2, 64);
        pr += __shfl_xor(pr, 1, 64);
        if (tid == 0) out[b] = pr + fcb[0];
    }
}

extern "C" void kernel_launch(void* const* d_in, const int* in_sizes, int n_in,
                              void* d_out, int out_size, void* d_ws, size_t ws_size,
                              hipStream_t stream) {
    const float* x    = (const float*)d_in[0];
    const float* Wih0 = (const float*)d_in[1];
    const float* Whh0 = (const float*)d_in[2];
    const float* bih0 = (const float*)d_in[3];
    const float* bhh0 = (const float*)d_in[4];
    const float* Wih1 = (const float*)d_in[5];
    const float* Whh1 = (const float*)d_in[6];
    const float* bih1 = (const float*)d_in[7];
    const float* bhh1 = (const float*)d_in[8];
    const float* fcw  = (const float*)d_in[9];
    const float* fcb  = (const float*)d_in[10];

    hipLaunchKernelGGL(lstm2_kernel, dim3(B_), dim3(NT), 0, stream,
                       x, Wih0, Whh0, bih0, bhh0, Wih1, Whh1, bih1, bhh1,
                       fcw, fcb, (float*)d_out);
}

// Round 8
// 683.191 us; speedup vs baseline: 2.1985x; 1.3806x over previous
//
#include <hip/hip_runtime.h>

#define B_ 512
#define T_ 1024
#define F_ 32
#define H0_ 64
#define H1_ 32
#define ROWS 2          // batch rows per block
#define NT 512          // 8 waves: 0-3 L0, 4-5 L1, 6-7 staging
#define CH 64           // x chunk (timesteps)
#define NCH (T_ / CH)

typedef _Float16 f16x8 __attribute__((ext_vector_type(8)));
typedef _Float16 f16x4 __attribute__((ext_vector_type(4)));
typedef float f32x4 __attribute__((ext_vector_type(4)));

__device__ __forceinline__ float exp2_f(float x) { return __builtin_amdgcn_exp2f(x); }

__device__ __forceinline__ f16x8 cvt8(const float* p) {
    float4 a = *(const float4*)p;
    float4 b = *(const float4*)(p + 4);
    f16x8 o;
    o[0] = (_Float16)a.x; o[1] = (_Float16)a.y; o[2] = (_Float16)a.z; o[3] = (_Float16)a.w;
    o[4] = (_Float16)b.x; o[5] = (_Float16)b.y; o[6] = (_Float16)b.z; o[7] = (_Float16)b.w;
    return o;
}
__device__ __forceinline__ f16x4 cvt4(float4 v) {
    f16x4 o;
    o[0] = (_Float16)v.x; o[1] = (_Float16)v.y; o[2] = (_Float16)v.z; o[3] = (_Float16)v.w;
    return o;
}

#define K_SIG (-1.4426950408889634f)   /* sigmoid: 1/(1+2^(k*x)) */
#define K_TNH (-2.8853900817779268f)   /* tanh = 2/(1+2^(k*x)) - 1 */

__global__ void __launch_bounds__(NT, 1) lstm2_mfma_kernel(
    const float* __restrict__ x,
    const float* __restrict__ Wih0, const float* __restrict__ Whh0,
    const float* __restrict__ bih0, const float* __restrict__ bhh0,
    const float* __restrict__ Wih1, const float* __restrict__ Whh1,
    const float* __restrict__ bih1, const float* __restrict__ bhh1,
    const float* __restrict__ fcw, const float* __restrict__ fcb,
    float* __restrict__ out)
{
    // x chunk staged f16, [step][row][feat]
    __shared__ __align__(16) _Float16 xch[2][CH][ROWS][F_];   // 16 KB
    // recurrent state, double buffered, [row][unit] (B-operand k-major per row)
    __shared__ __align__(16) _Float16 h0b[2][ROWS][H0_];      // 512 B
    __shared__ __align__(16) _Float16 h1b[2][ROWS][H1_];      // 256 B
    // per-wave gate scatter scratch: [G][row][u_local] f32 (128 floats/wave)
    __shared__ __align__(16) float wscr[6][128];              // 3 KB
    __shared__ float h1fin[ROWS][H1_];

    const int tid = threadIdx.x, blk = blockIdx.x;
    const int wv = tid >> 6, lane = tid & 63;
    const int lrow = lane & 15;      // A-frag M row / B-frag N col (mod 16)
    const int lk   = lane >> 4;      // k-chunk-of-8 selector
    const bool isL0 = (wv < 4);
    const bool isL1 = (wv == 4 || wv == 5);
    const int U0 = isL0 ? 16 * wv : 16 * (wv - 4);   // unit-group base

    // ---------------- preload W as MFMA A-fragments ----------------
    // A-frag elem j = W[16t + (lane&15)][8*(lane>>4) + j]  (K-contiguous)
    f16x8 aw[4][3];
    if (isL0) {
#pragma unroll
        for (int G = 0; G < 4; ++G) {
            const int r = G * H0_ + U0 + lrow;
            aw[G][0] = cvt8(&Wih0[r * F_ + 8 * lk]);          // k 0..31  (x)
            aw[G][1] = cvt8(&Whh0[r * H0_ + 8 * lk]);         // k 32..63 (h0 lo)
            aw[G][2] = cvt8(&Whh0[r * H0_ + 32 + 8 * lk]);    // k 64..95 (h0 hi)
        }
    } else if (isL1) {
#pragma unroll
        for (int G = 0; G < 4; ++G) {
            const int r = G * H1_ + U0 + lrow;
            aw[G][0] = cvt8(&Wih1[r * H0_ + 8 * lk]);         // k 0..31  (h0 lo)
            aw[G][1] = cvt8(&Wih1[r * H0_ + 32 + 8 * lk]);    // k 32..63 (h0 hi)
            aw[G][2] = cvt8(&Whh1[r * H1_ + 8 * lk]);         // k 64..95 (h1)
        }
    }

    // ---------------- per-lane activation constants ----------------
    // scratch value index v = G*32 + row*16 + u_local; lane reads v=lane (slot0: G 0,1)
    // and v=64+lane (slot1: G 2,3). slot0: i,f -> sigmoid. slot1: g(tanh) lanes<32, o(sig) lanes>=32.
    const float kS1 = (lane < 32) ? K_TNH : K_SIG;
    const float kA1 = (lane < 32) ? 2.0f : 1.0f;
    const float kC1 = (lane < 32) ? -1.0f : 0.0f;
    float bK0 = 0.0f, bK1 = 0.0f;
    if (isL0) {
        const int r0 = (lane >> 5) * H0_ + U0 + (lane & 15);
        const int r1 = (2 + (lane >> 5)) * H0_ + U0 + (lane & 15);
        bK0 = (bih0[r0] + bhh0[r0]) * K_SIG;
        bK1 = (bih0[r1] + bhh0[r1]) * kS1;
    } else if (isL1) {
        const int r0 = (lane >> 5) * H1_ + U0 + (lane & 15);
        const int r1 = (2 + (lane >> 5)) * H1_ + U0 + (lane & 15);
        bK0 = (bih1[r0] + bhh1[r0]) * K_SIG;
        bK1 = (bih1[r1] + bhh1[r1]) * kS1;
    }

    // ---------------- stage chunk 0 + zero state ----------------
    {
        const float4* x4 = (const float4*)x;
#pragma unroll
        for (int k = 0; k < 2; ++k) {
            const int i = tid + k * NT;                 // 0..1023
            const int b = i >> 9, rem = i & 511;
            const int s2 = rem >> 3, f4 = rem & 7;
            float4 v = x4[(size_t)(2 * blk + b) * (T_ * (F_ / 4)) + s2 * (F_ / 4) + f4];
            *(f16x4*)&xch[0][s2][b][f4 * 4] = cvt4(v);
        }
    }
    if (tid < 256) ((_Float16*)h0b)[tid] = (_Float16)0.0f;
    if (tid < 128) ((_Float16*)h1b)[tid] = (_Float16)0.0f;
    __syncthreads();

    // ---------------- main recurrence: 1025 iterations ----------------
    // iter it: L0 computes h0[it] (it<1024); L1 computes h1[it-1] (it>=1). One barrier/iter.
    int p = 0, cb = 0;
    float c = 0.0f, hreg = 0.0f;   // valid in lanes<32 of compute waves
    for (int it = 0; it <= T_; ++it) {
        const int s = it & (CH - 1);
        const bool active = (isL0 && it < T_) || (isL1 && it >= 1);
        if (active) {
            // B-fragments: elem j = z[8*lk + j][col], col parity = lane&1 (cols>=2 duplicate)
            f16x8 b0, b1, b2;
            if (isL0) {
                b0 = *(const f16x8*)&xch[cb][s][lane & 1][8 * lk];
                b1 = *(const f16x8*)&h0b[p][lane & 1][8 * lk];
                b2 = *(const f16x8*)&h0b[p][lane & 1][32 + 8 * lk];
            } else {
                b0 = *(const f16x8*)&h0b[p][lane & 1][8 * lk];
                b1 = *(const f16x8*)&h0b[p][lane & 1][32 + 8 * lk];
                b2 = *(const f16x8*)&h1b[p][lane & 1][8 * lk];
            }
            // 12 MFMA: gates[G] tile = W[G] @ z   (D: col=lane&15, row=(lane>>4)*4+reg)
            f32x4 acc[4];
#pragma unroll
            for (int G = 0; G < 4; ++G) {
                f32x4 a = {0.f, 0.f, 0.f, 0.f};
                a = __builtin_amdgcn_mfma_f32_16x16x32_f16(aw[G][0], b0, a, 0, 0, 0);
                a = __builtin_amdgcn_mfma_f32_16x16x32_f16(aw[G][1], b1, a, 0, 0, 0);
                a = __builtin_amdgcn_mfma_f32_16x16x32_f16(aw[G][2], b2, a, 0, 0, 0);
                acc[G] = a;
            }
            // scatter valid cols (batch 0,1) -> [G][row][u_local] f32; u_local = lk*4+reg
            if (lrow < 2) {
                float* sp = &wscr[wv][lrow * 16 + lk * 4];
#pragma unroll
                for (int G = 0; G < 4; ++G) {
                    *(float2*)&sp[G * 32]     = make_float2(acc[G][0], acc[G][1]);
                    *(float2*)&sp[G * 32 + 2] = make_float2(acc[G][2], acc[G][3]);
                }
            }
            // one activation per gate value (2 per lane)
            const float v0 = wscr[wv][lane];        // G = lane>>5 in {i,f}: sigmoid
            const float v1 = wscr[wv][64 + lane];   // G = 2+(lane>>5) in {g,o}
            const float act0 = __builtin_amdgcn_rcpf(1.0f + exp2_f(fmaf(v0, K_SIG, bK0)));
            const float rr1  = __builtin_amdgcn_rcpf(1.0f + exp2_f(fmaf(v1, kS1, bK1)));
            const float act1 = fmaf(kA1, rr1, kC1);
            // assemble i,f,g,o at lanes<32 (elem: row=lane>>4, u_local=lane&15)
            const float fg = __shfl_xor(act0, 32, 64);   // f
            const float og = __shfl_xor(act1, 32, 64);   // o
            c = fmaf(fg, c, act0 * act1);                // c = f*c + i*g
            const float thr = __builtin_amdgcn_rcpf(1.0f + exp2_f(c * K_TNH));
            const float thc = fmaf(2.0f, thr, -1.0f);
            hreg = og * thc;
            if (lane < 32) {
                const _Float16 hq = (_Float16)hreg;
                if (isL0) h0b[p ^ 1][lane >> 4][U0 + (lane & 15)] = hq;
                else      h1b[p ^ 1][lane >> 4][U0 + (lane & 15)] = hq;
            }
        }
        if (wv >= 6) {
            // stage next x chunk during first iteration of each chunk
            if (s == 0 && (it >> 6) < (NCH - 1)) {
                const int tbase = it + CH;
                const float4* x4 = (const float4*)x;
                const int ls = tid - 384;               // 0..127
#pragma unroll
                for (int k = 0; k < 8; ++k) {
                    const int i = ls + k * 128;         // 0..1023
                    const int b = i >> 9, rem = i & 511;
                    const int s2 = rem >> 3, f4 = rem & 7;
                    float4 v = x4[(size_t)(2 * blk + b) * (T_ * (F_ / 4)) + (tbase + s2) * (F_ / 4) + f4];
                    *(f16x4*)&xch[cb ^ 1][s2][b][f4 * 4] = cvt4(v);
                }
            }
        }
        __syncthreads();
        p ^= 1;
        if (s == CH - 1) cb ^= 1;
    }

    // ---------------- epilogue ----------------
    float* hT0 = out + B_;
    float* cT0 = hT0 + B_ * H0_;
    float* hT1 = cT0 + B_ * H0_;
    float* cT1 = hT1 + B_ * H1_;
    if (isL0 && lane < 32) {
        const int row = 2 * blk + (lane >> 4), unit = U0 + (lane & 15);
        hT0[row * H0_ + unit] = hreg;
        cT0[row * H0_ + unit] = c;
    }
    if (isL1 && lane < 32) {
        const int row = 2 * blk + (lane >> 4), unit = U0 + (lane & 15);
        hT1[row * H1_ + unit] = hreg;
        cT1[row * H1_ + unit] = c;
        h1fin[lane >> 4][unit] = hreg;
    }
    __syncthreads();
    if (wv == 0) {
        const int u = lane & 31, r = lane >> 5;
        float v = h1fin[r][u] * fcw[u];
        v += __shfl_xor(v, 16, 64);
        v += __shfl_xor(v, 8, 64);
        v += __shfl_xor(v, 4, 64);
        v += __shfl_xor(v, 2, 64);
        v += __shfl_xor(v, 1, 64);
        if (u == 0) out[2 * blk + r] = v + fcb[0];
    }
}

extern "C" void kernel_launch(void* const* d_in, const int* in_sizes, int n_in,
                              void* d_out, int out_size, void* d_ws, size_t ws_size,
                              hipStream_t stream) {
    const float* x    = (const float*)d_in[0];
    const float* Wih0 = (const float*)d_in[1];
    const float* Whh0 = (const float*)d_in[2];
    const float* bih0 = (const float*)d_in[3];
    const float* bhh0 = (const float*)d_in[4];
    const float* Wih1 = (const float*)d_in[5];
    const float* Whh1 = (const float*)d_in[6];
    const float* bih1 = (const float*)d_in[7];
    const float* bhh1 = (const float*)d_in[8];
    const float* fcw  = (const float*)d_in[9];
    const float* fcb  = (const float*)d_in[10];

    hipLaunchKernelGGL(lstm2_mfma_kernel, dim3(B_ / ROWS), dim3(NT), 0, stream,
                       x, Wih0, Whh0, bih0, bhh0, Wih1, Whh1, bih1, bhh1,
                       fcw, fcb, (float*)d_out);
}